// Round 8
// baseline (218.929 us; speedup 1.0000x reference)
//
#include <hip/hip_runtime.h>
#include <math.h>

typedef short bf16x8 __attribute__((ext_vector_type(8)));
typedef float f32x16 __attribute__((ext_vector_type(16)));
typedef float f32x4 __attribute__((ext_vector_type(4)));
typedef unsigned u32x4 __attribute__((ext_vector_type(4)));

#define NF 4
#define D0 8
#define LPE_OUT 24

// ---------------- ws byte layout ----------------
// [0,16896)  bf16 A-frags + C-layout biases (prep)
#define PART_OFF   17408ULL                   // 4096 rows x 512 buckets u32 = 8 MB
#define TOT_OFF    8406016ULL                 // totals[512]
#define SCOORD_OFF 8408064ULL                 // sorted float2 coords, 8 MB
#define PERM_OFF   16796672ULL                // u32 perm, 4 MB
#define WS_NEED    20990976ULL

#define NBUCKET 512                            // 32 v-rows x 16 u-cols

// ---------- bf16 helpers ----------
__device__ __forceinline__ unsigned f2bf(float x) {
    unsigned u = __float_as_uint(x);
    u = u + 0x7fffu + ((u >> 16) & 1u);
    return u >> 16;
}
__device__ __forceinline__ unsigned pkbf(float a, float b) {
    return f2bf(a) | (f2bf(b) << 16);
}
__device__ __forceinline__ bf16x8 mkfrag(unsigned w0, unsigned w1, unsigned w2, unsigned w3) {
    u32x4 u = { w0, w1, w2, w3 };
    return __builtin_bit_cast(bf16x8, u);
}

// ---------- weight prep body (R3..R7-verified) ----------
__device__ void prep_body(const float* __restrict__ w0, const float* __restrict__ b0,
                          const float* __restrict__ w1, const float* __restrict__ b1,
                          const float* __restrict__ w2, float* __restrict__ ws, int t)
{
    unsigned short* a0 = (unsigned short*)ws;
    unsigned short* a1 = a0 + 2048;
    unsigned short* a2 = a1 + 4096;
    float* b0c = (float*)(a2 + 2048);
    float* b1c = b0c + 64;

    for (int e = t; e < 2048; e += 256) {
        int tile = e >> 9, lane = (e >> 3) & 63, j = e & 7;
        int m = tile >> 1, ks = tile & 1;
        int row = m * 32 + (lane & 31);
        int k = ks * 16 + (lane >> 5) * 8 + j;
        float v = (k < 26) ? w0[k * 64 + row] : 0.f;
        a0[e] = (unsigned short)f2bf(v);
    }
    for (int e = t; e < 4096; e += 256) {
        int tile = e >> 9, lane = (e >> 3) & 63, j = e & 7;
        int m = tile >> 2, ks = tile & 3;
        int row = m * 32 + (lane & 31);
        int k = ks * 16 + (lane >> 5) * 8 + j;
        a1[e] = (unsigned short)f2bf(w1[k * 64 + row]);
    }
    for (int e = t; e < 2048; e += 256) {
        int ks = e >> 9, lane = (e >> 3) & 63, j = e & 7;
        int row = lane & 31;
        int k = ks * 16 + (lane >> 5) * 8 + j;
        float v = (row < 4) ? w2[k * 4 + row] : 0.f;
        a2[e] = (unsigned short)f2bf(v);
    }
    if (t < 64) {
        int m = t >> 5, q5 = (t >> 4) & 1, r = t & 15;
        int row = (r & 3) + 8 * (r >> 2) + 4 * q5;
        b0c[(m * 2 + q5) * 16 + r] = b0[m * 32 + row];
        b1c[(m * 2 + q5) * 16 + r] = b1[m * 32 + row];
    }
}

__global__ void prep_kernel(const float* __restrict__ w0, const float* __restrict__ b0,
                            const float* __restrict__ w1, const float* __restrict__ b1,
                            const float* __restrict__ w2, float* __restrict__ ws)
{
    prep_body(w0, b0, w1, b1, w2, ws, threadIdx.x);
}

// ================= counting sort into 512 uv-buckets =================
__device__ __forceinline__ int bucket_of(float cx, float cy) {
    float u = fminf(fmaxf(cx, 0.f), 1.f - 1e-6f);
    float v = fminf(fmaxf(cy, 0.f), 1.f - 1e-6f);
    return (int)(v * 32.f) * 16 + (int)(u * 16.f);
}

// histogram (+ fused weight prep as block 4096); totals via global atomics
__global__ __launch_bounds__(256)
void prep_hist(const float2* __restrict__ coords, unsigned* __restrict__ part,
               unsigned* __restrict__ totals,
               const float* __restrict__ w0, const float* __restrict__ b0,
               const float* __restrict__ w1, const float* __restrict__ b1,
               const float* __restrict__ w2, float* __restrict__ ws)
{
    int t = threadIdx.x;
    if (blockIdx.x == 4096) { prep_body(w0, b0, w1, b1, w2, ws, t); return; }
    __shared__ unsigned h[NBUCKET];
    h[t] = 0; h[t + 256] = 0;
    __syncthreads();
    float2 c = coords[blockIdx.x * 256 + t];
    atomicAdd(&h[bucket_of(c.x, c.y)], 1u);
    __syncthreads();
    unsigned v0 = h[t], v1 = h[t + 256];
    part[(unsigned long long)blockIdx.x * NBUCKET + t] = v0;
    part[(unsigned long long)blockIdx.x * NBUCKET + 256 + t] = v1;
    if (v0) atomicAdd(&totals[t], v0);
    if (v1) atomicAdd(&totals[t + 256], v1);
}

// per-bucket: exclusive prefix of totals (in-block) + column scan -> offsets in place
__global__ __launch_bounds__(256)
void sort_offsets(unsigned* __restrict__ part, const unsigned* __restrict__ totals)
{
    int bucket = blockIdx.x, t = threadIdx.x;

    __shared__ unsigned red[256];
    unsigned s0 = (t < bucket) ? totals[t] : 0u;
    if (t + 256 < bucket) s0 += totals[t + 256];
    red[t] = s0;
    __syncthreads();
    for (int off = 128; off > 0; off >>= 1) {
        if (t < off) red[t] += red[t + off];
        __syncthreads();
    }
    unsigned start = red[0];
    __syncthreads();

    unsigned loc[16];
    unsigned s = 0;
#pragma unroll
    for (int k = 0; k < 16; ++k) {
        loc[k] = part[(unsigned long long)(16 * t + k) * NBUCKET + bucket];
        s += loc[k];
    }
    __shared__ unsigned sc[256];
    sc[t] = s;
    __syncthreads();
    for (int off = 1; off < 256; off <<= 1) {
        unsigned v = (t >= off) ? sc[t - off] : 0u;
        __syncthreads();
        sc[t] += v;
        __syncthreads();
    }
    unsigned base = start + sc[t] - s;
#pragma unroll
    for (int k = 0; k < 16; ++k) {
        unsigned tmp = loc[k];
        part[(unsigned long long)(16 * t + k) * NBUCKET + bucket] = base;
        base += tmp;
    }
}

__global__ __launch_bounds__(256)
void sort_scatter(const float2* __restrict__ coords, const unsigned* __restrict__ offs,
                  float2* __restrict__ scoord, unsigned* __restrict__ perm)
{
    __shared__ unsigned cnt[NBUCKET];
    __shared__ unsigned base[NBUCKET];
    int t = threadIdx.x;
    cnt[t] = 0; cnt[t + 256] = 0;
    base[t] = offs[(unsigned long long)blockIdx.x * NBUCKET + t];
    base[t + 256] = offs[(unsigned long long)blockIdx.x * NBUCKET + 256 + t];
    __syncthreads();
    int i = blockIdx.x * 256 + t;
    float2 c = coords[i];
    int b = bucket_of(c.x, c.y);
    unsigned r = atomicAdd(&cnt[b], 1u);
    unsigned slot = base[b] + r;
    scoord[slot] = c;
    perm[slot] = (unsigned)i;
}

// ================= shared MLP pipeline (R4..R7-verified math) =================
__device__ __forceinline__ void mlp_pair(const unsigned (&B0)[2][2][4],
                                         const float* __restrict__ ws,
                                         const float* __restrict__ b2,
                                         int lane, int q5, f32x16 (&acc2)[2])
{
    const bf16x8* A0 = (const bf16x8*)ws;
    const bf16x8* A1 = (const bf16x8*)((const char*)ws + 4096);
    const bf16x8* A2 = (const bf16x8*)((const char*)ws + 12288);
    const float4* b0c = (const float4*)((const char*)ws + 16384);
    const float4* b1c = (const float4*)((const char*)ws + 16640);

    unsigned B1[4][2][4];
#pragma unroll
    for (int m = 0; m < 2; ++m) {
        f32x16 acc[2];
#pragma unroll
        for (int cc = 0; cc < 4; ++cc) {
            float4 bq = b0c[(m * 2 + q5) * 4 + cc];
#pragma unroll
            for (int n = 0; n < 2; ++n) {
                acc[n][4 * cc + 0] = bq.x;
                acc[n][4 * cc + 1] = bq.y;
                acc[n][4 * cc + 2] = bq.z;
                acc[n][4 * cc + 3] = bq.w;
            }
        }
#pragma unroll
        for (int ks = 0; ks < 2; ++ks) {
            bf16x8 af = A0[(m * 2 + ks) * 64 + lane];
#pragma unroll
            for (int n = 0; n < 2; ++n)
                acc[n] = __builtin_amdgcn_mfma_f32_32x32x16_bf16(
                    af, mkfrag(B0[ks][n][0], B0[ks][n][1], B0[ks][n][2], B0[ks][n][3]),
                    acc[n], 0, 0, 0);
        }
#pragma unroll
        for (int t = 0; t < 2; ++t) {
#pragma unroll
            for (int n = 0; n < 2; ++n)
#pragma unroll
                for (int c = 0; c < 2; ++c) {
                    int r0 = 2 * c + 8 * t;
                    int r1 = 2 * c + 8 * t + 4;
                    unsigned P0 = pkbf(fmaxf(acc[n][r0], 0.f), fmaxf(acc[n][r0 + 1], 0.f));
                    unsigned P1 = pkbf(fmaxf(acc[n][r1], 0.f), fmaxf(acc[n][r1 + 1], 0.f));
                    auto r = __builtin_amdgcn_permlane32_swap(P1, P0, false, false);
                    B1[2 * m + t][n][c] = r[1];
                    B1[2 * m + t][n][2 + c] = r[0];
                }
        }
    }

    unsigned B2[4][2][4];
#pragma unroll
    for (int m = 0; m < 2; ++m) {
        f32x16 acc[2];
#pragma unroll
        for (int cc = 0; cc < 4; ++cc) {
            float4 bq = b1c[(m * 2 + q5) * 4 + cc];
#pragma unroll
            for (int n = 0; n < 2; ++n) {
                acc[n][4 * cc + 0] = bq.x;
                acc[n][4 * cc + 1] = bq.y;
                acc[n][4 * cc + 2] = bq.z;
                acc[n][4 * cc + 3] = bq.w;
            }
        }
#pragma unroll
        for (int ks = 0; ks < 4; ++ks) {
            bf16x8 af = A1[(m * 4 + ks) * 64 + lane];
#pragma unroll
            for (int n = 0; n < 2; ++n)
                acc[n] = __builtin_amdgcn_mfma_f32_32x32x16_bf16(
                    af, mkfrag(B1[ks][n][0], B1[ks][n][1], B1[ks][n][2], B1[ks][n][3]),
                    acc[n], 0, 0, 0);
        }
#pragma unroll
        for (int t = 0; t < 2; ++t) {
#pragma unroll
            for (int n = 0; n < 2; ++n)
#pragma unroll
                for (int c = 0; c < 2; ++c) {
                    int r0 = 2 * c + 8 * t;
                    int r1 = 2 * c + 8 * t + 4;
                    unsigned P0 = pkbf(fmaxf(acc[n][r0], 0.f), fmaxf(acc[n][r0 + 1], 0.f));
                    unsigned P1 = pkbf(fmaxf(acc[n][r1], 0.f), fmaxf(acc[n][r1 + 1], 0.f));
                    auto r = __builtin_amdgcn_permlane32_swap(P1, P0, false, false);
                    B2[2 * m + t][n][c] = r[1];
                    B2[2 * m + t][n][2 + c] = r[0];
                }
        }
    }

#pragma unroll
    for (int n = 0; n < 2; ++n)
#pragma unroll
        for (int r = 0; r < 16; ++r) acc2[n][r] = (r < 4) ? b2[r] : 0.f;
#pragma unroll
    for (int ks = 0; ks < 4; ++ks) {
        bf16x8 af = A2[ks * 64 + lane];
#pragma unroll
        for (int n = 0; n < 2; ++n)
            acc2[n] = __builtin_amdgcn_mfma_f32_32x32x16_bf16(
                af, mkfrag(B2[ks][n][0], B2[ks][n][1], B2[ks][n][2], B2[ks][n][3]),
                acc2[n], 0, 0, 0);
    }
}

// ---- fp32 gather macros (address -> batched loads -> consume) ----
#define GAF(IDX, R) int bA##IDX; float luA##IDX, lvA##IDX; \
    { float fu_ = uA * (float)((R) - 1), fv_ = vA * (float)((R) - 1); \
      int i0_ = (int)floorf(fu_), j0_ = (int)floorf(fv_); \
      i0_ = i0_ < 0 ? 0 : (i0_ > (R) - 2 ? (R) - 2 : i0_); \
      j0_ = j0_ < 0 ? 0 : (j0_ > (R) - 2 ? (R) - 2 : j0_); \
      luA##IDX = fu_ - (float)i0_; lvA##IDX = fv_ - (float)j0_; \
      bA##IDX = i0_ + j0_ * (R); }

#define GLF(IDX, R, G) \
    float2 tA##IDX##_0 = (G)[bA##IDX],       tA##IDX##_1 = (G)[bA##IDX + 1], \
           tA##IDX##_2 = (G)[bA##IDX + (R)], tA##IDX##_3 = (G)[bA##IDX + (R) + 1];

#define GSF(IDX) { \
    float omu_ = 1.f - luA##IDX, omv_ = 1.f - lvA##IDX; \
    float w00_ = omu_ * omv_, w10_ = luA##IDX * omv_, w01_ = omu_ * lvA##IDX, w11_ = luA##IDX * lvA##IDX; \
    e0A += tA##IDX##_0.x * w00_ + tA##IDX##_1.x * w10_ + tA##IDX##_2.x * w01_ + tA##IDX##_3.x * w11_; \
    e1A += tA##IDX##_0.y * w00_ + tA##IDX##_1.y * w10_ + tA##IDX##_2.y * w01_ + tA##IDX##_3.y * w11_; }

// ---------- main sorted kernel: fp32 gathers, hw trig, MFMA MLP ----------
__global__ __launch_bounds__(256, 4)
void colornet_sorted(const float2* __restrict__ pts,
                     const unsigned* __restrict__ perm,
                     const float2* __restrict__ g0, const float2* __restrict__ g1,
                     const float2* __restrict__ g2, const float2* __restrict__ g3,
                     const float2* __restrict__ g4, const float2* __restrict__ g5,
                     const float2* __restrict__ g6, const float2* __restrict__ g7,
                     const float* __restrict__ lpe,
                     const float* __restrict__ ws,
                     const float* __restrict__ b2,
                     f32x4* __restrict__ out)
{
    const int lane = threadIdx.x & 63;
    const int wave = threadIdx.x >> 6;
    const int q5 = lane >> 5;
    // XCD-chunk swizzle (gridDim.x = 4096, multiple of 8 -> bijective)
    int bid = blockIdx.x;
    int cpx = gridDim.x >> 3;
    bid = (bid & 7) * cpx + (bid >> 3);
    const int base_pt = bid * 256 + wave * 64;

    float2 c = pts[base_pt + lane];
    float uA = fminf(fmaxf(c.x, 0.f), 1.f - 1e-6f);
    float vA = fminf(fmaxf(c.y, 0.f), 1.f - 1e-6f);

    float e0A = 0.f, e1A = 0.f;

    // addresses for all levels, then batched loads (compiler schedules)
    GAF(7, 2048) GAF(6, 1024) GAF(5, 512) GAF(4, 256)
    GAF(3, 128)  GAF(2, 64)   GAF(1, 32)  GAF(0, 16)

    GLF(7, 2048, g7)
    GLF(6, 1024, g6)
    GLF(5, 512,  g5)
    GLF(4, 256,  g4)
    GLF(3, 128,  g3)
    GLF(2, 64,   g2)
    GLF(1, 32,   g1)
    GLF(0, 16,   g0)

    // LPE addresses + fp32 loads (R4-verified layout)
    float coeffA[LPE_OUT];
    float lu_pe, lv_pe;
    {
        float fu = uA * 128.f, fv = vA * 128.f;
        int i0 = (int)floorf(fu);
        int j0 = (int)floorf(fv);
        i0 = i0 < 0 ? 0 : (i0 > 127 ? 127 : i0);
        j0 = j0 < 0 ? 0 : (j0 > 127 ? 127 : j0);
        lu_pe = fu - (float)i0;
        lv_pe = fv - (float)j0;
        int base = (i0 + j0 * 129) * LPE_OUT;
        const float4* p00 = (const float4*)(lpe + base);
        const float4* p10 = (const float4*)(lpe + base + LPE_OUT);
        const float4* p01 = (const float4*)(lpe + base + 129 * LPE_OUT);
        const float4* p11 = (const float4*)(lpe + base + 130 * LPE_OUT);
        float omu = 1.f - lu_pe, omv = 1.f - lv_pe;
        float w00 = omu * omv, w10 = lu_pe * omv, w01 = omu * lv_pe, w11 = lu_pe * lv_pe;
#pragma unroll
        for (int q = 0; q < 6; ++q) {
            float4 a = p00[q], bq = p10[q], cq = p01[q], dq = p11[q];
            coeffA[4 * q + 0] = a.x * w00 + bq.x * w10 + cq.x * w01 + dq.x * w11;
            coeffA[4 * q + 1] = a.y * w00 + bq.y * w10 + cq.y * w01 + dq.y * w11;
            coeffA[4 * q + 2] = a.z * w00 + bq.z * w10 + cq.z * w01 + dq.z * w11;
            coeffA[4 * q + 3] = a.w * w00 + bq.w * w10 + cq.w * w01 + dq.w * w11;
        }
    }

    // hw trig: args are exact revolutions (freq = 2^k * 2pi)
    float peA[16];
#pragma unroll
    for (int kf = 0; kf < NF; ++kf) {
        float au = lu_pe * (float)(1 << kf);
        float av = lv_pe * (float)(1 << kf);
        float fu_ = __builtin_amdgcn_fractf(au);
        float fv_ = __builtin_amdgcn_fractf(av);
        peA[kf]          = __builtin_amdgcn_cosf(fu_);
        peA[NF + kf]     = __builtin_amdgcn_sinf(fu_);
        peA[2 * NF + kf] = __builtin_amdgcn_cosf(fv_);
        peA[3 * NF + kf] = __builtin_amdgcn_sinf(fv_);
    }

    // consume grid taps (issue order: far levels first)
    GSF(7) GSF(6) GSF(5) GSF(4) GSF(3) GSF(2) GSF(1) GSF(0)

    // features -> bf16 pack
    unsigned fdA[16];
    {
        float feat[32];
        feat[0] = e0A; feat[1] = e1A;
#pragma unroll
        for (int q = 0; q < D0; ++q) feat[2 + q] = coeffA[q];
#pragma unroll
        for (int q = 0; q < 4 * NF; ++q) feat[2 + D0 + q] = coeffA[D0 + q] * peA[q];
#pragma unroll
        for (int q = 26; q < 32; ++q) feat[q] = 0.f;
#pragma unroll
        for (int i = 0; i < 16; ++i) fdA[i] = pkbf(feat[2 * i], feat[2 * i + 1]);
    }

    // B0 fragments via permlane32_swap (R4-verified)
    unsigned B0a[2][2][4];
#pragma unroll
    for (int ks = 0; ks < 2; ++ks)
#pragma unroll
        for (int j2 = 0; j2 < 4; ++j2) {
            unsigned a = fdA[8 * ks + j2];
            unsigned b = fdA[8 * ks + 4 + j2];
            auto r = __builtin_amdgcn_permlane32_swap(b, a, false, false);
            B0a[ks][1][j2] = r[0];
            B0a[ks][0][j2] = r[1];
        }

    f32x16 acc2[2];
    mlp_pair(B0a, ws, b2, lane, q5, acc2);

    if (lane < 32) {
#pragma unroll
        for (int n = 0; n < 2; ++n) {
            f32x4 o;
            o[0] = 1.f / (1.f + __expf(-acc2[n][0]));
            o[1] = 1.f / (1.f + __expf(-acc2[n][1]));
            o[2] = 1.f / (1.f + __expf(-acc2[n][2]));
            o[3] = 1.f / (1.f + __expf(-acc2[n][3]));
            int oi = (int)perm[base_pt + 32 * n + lane];
            __builtin_nontemporal_store(o, out + oi);
        }
    }
}

// ---------- fp32 single-point unsorted fallback (R6/R7-verified) ----------
template<int R>
__device__ __forceinline__ void gather_level(const float* __restrict__ g,
                                             float u, float v,
                                             float& e0, float& e1) {
    const float scale = (float)(R - 1);
    float fu = u * scale, fv = v * scale;
    int i0 = (int)floorf(fu);
    int j0 = (int)floorf(fv);
    i0 = i0 < 0 ? 0 : (i0 > R - 2 ? R - 2 : i0);
    j0 = j0 < 0 ? 0 : (j0 > R - 2 ? R - 2 : j0);
    float lu = fu - (float)i0;
    float lv = fv - (float)j0;
    const float2* gg = (const float2*)g;
    int base = i0 + j0 * R;
    float2 f00 = gg[base];
    float2 f10 = gg[base + 1];
    float2 f01 = gg[base + R];
    float2 f11 = gg[base + R + 1];
    float omu = 1.f - lu, omv = 1.f - lv;
    float w00 = omu * omv, w10 = lu * omv, w01 = omu * lv, w11 = lu * lv;
    e0 += f00.x * w00 + f10.x * w10 + f01.x * w01 + f11.x * w11;
    e1 += f00.y * w00 + f10.y * w10 + f01.y * w01 + f11.y * w11;
}

__global__ __launch_bounds__(256, 4)
void colornet_fp32(const float* __restrict__ coords,
                   const float* __restrict__ g0, const float* __restrict__ g1,
                   const float* __restrict__ g2, const float* __restrict__ g3,
                   const float* __restrict__ g4, const float* __restrict__ g5,
                   const float* __restrict__ g6, const float* __restrict__ g7,
                   const float* __restrict__ lpe,
                   const float* __restrict__ ws,
                   const float* __restrict__ b2,
                   f32x4* __restrict__ out)
{
    const int lane = threadIdx.x & 63;
    const int wave = threadIdx.x >> 6;
    const int q5 = lane >> 5;
    const int base_pt = blockIdx.x * 256 + wave * 64;
    const int point = base_pt + lane;

    const float* cp = coords + 2 * point;
    float cx = __builtin_nontemporal_load(cp);
    float cy = __builtin_nontemporal_load(cp + 1);
    float uA = fminf(fmaxf(cx, 0.f), 1.f - 1e-6f);
    float vA = fminf(fmaxf(cy, 0.f), 1.f - 1e-6f);

    float e0 = 0.f, e1 = 0.f;
    gather_level<16>(g0, uA, vA, e0, e1);
    gather_level<32>(g1, uA, vA, e0, e1);
    gather_level<64>(g2, uA, vA, e0, e1);
    gather_level<128>(g3, uA, vA, e0, e1);
    gather_level<256>(g4, uA, vA, e0, e1);
    gather_level<512>(g5, uA, vA, e0, e1);
    gather_level<1024>(g6, uA, vA, e0, e1);
    gather_level<2048>(g7, uA, vA, e0, e1);

    float coeff[LPE_OUT];
    float lu_pe, lv_pe;
    {
        float fu = uA * 128.f, fv = vA * 128.f;
        int i0 = (int)floorf(fu);
        int j0 = (int)floorf(fv);
        i0 = i0 < 0 ? 0 : (i0 > 127 ? 127 : i0);
        j0 = j0 < 0 ? 0 : (j0 > 127 ? 127 : j0);
        lu_pe = fu - (float)i0;
        lv_pe = fv - (float)j0;
        int base = (i0 + j0 * 129) * LPE_OUT;
        const float4* p00 = (const float4*)(lpe + base);
        const float4* p10 = (const float4*)(lpe + base + LPE_OUT);
        const float4* p01 = (const float4*)(lpe + base + 129 * LPE_OUT);
        const float4* p11 = (const float4*)(lpe + base + 130 * LPE_OUT);
        float omu = 1.f - lu_pe, omv = 1.f - lv_pe;
        float w00 = omu * omv, w10 = lu_pe * omv, w01 = omu * lv_pe, w11 = lu_pe * lv_pe;
#pragma unroll
        for (int q = 0; q < 6; ++q) {
            float4 a = p00[q], bq = p10[q], cq = p01[q], dq = p11[q];
            coeff[4 * q + 0] = a.x * w00 + bq.x * w10 + cq.x * w01 + dq.x * w11;
            coeff[4 * q + 1] = a.y * w00 + bq.y * w10 + cq.y * w01 + dq.y * w11;
            coeff[4 * q + 2] = a.z * w00 + bq.z * w10 + cq.z * w01 + dq.z * w11;
            coeff[4 * q + 3] = a.w * w00 + bq.w * w10 + cq.w * w01 + dq.w * w11;
        }
    }

    float pe[16];
#pragma unroll
    for (int kf = 0; kf < NF; ++kf) {
        const float fr = 6.28318530717958647692f * (float)(1 << kf);
        float au = lu_pe * fr;
        float av = lv_pe * fr;
        pe[kf]          = __cosf(au);
        pe[NF + kf]     = __sinf(au);
        pe[2 * NF + kf] = __cosf(av);
        pe[3 * NF + kf] = __sinf(av);
    }

    float feat[32];
    feat[0] = e0; feat[1] = e1;
#pragma unroll
    for (int q = 0; q < D0; ++q) feat[2 + q] = coeff[q];
#pragma unroll
    for (int q = 0; q < 4 * NF; ++q) feat[2 + D0 + q] = coeff[D0 + q] * pe[q];
#pragma unroll
    for (int q = 26; q < 32; ++q) feat[q] = 0.f;

    unsigned fd[16];
#pragma unroll
    for (int i = 0; i < 16; ++i) fd[i] = pkbf(feat[2 * i], feat[2 * i + 1]);

    unsigned B0[2][2][4];
#pragma unroll
    for (int ks = 0; ks < 2; ++ks)
#pragma unroll
        for (int j2 = 0; j2 < 4; ++j2) {
            unsigned a = fd[8 * ks + j2];
            unsigned b = fd[8 * ks + 4 + j2];
            auto r = __builtin_amdgcn_permlane32_swap(b, a, false, false);
            B0[ks][1][j2] = r[0];
            B0[ks][0][j2] = r[1];
        }

    f32x16 acc2[2];
    mlp_pair(B0, ws, b2, lane, q5, acc2);
    if (lane < 32) {
#pragma unroll
        for (int n = 0; n < 2; ++n) {
            f32x4 o;
            o[0] = 1.f / (1.f + __expf(-acc2[n][0]));
            o[1] = 1.f / (1.f + __expf(-acc2[n][1]));
            o[2] = 1.f / (1.f + __expf(-acc2[n][2]));
            o[3] = 1.f / (1.f + __expf(-acc2[n][3]));
            __builtin_nontemporal_store(o, out + (base_pt + 32 * n + lane));
        }
    }
}

extern "C" void kernel_launch(void* const* d_in, const int* in_sizes, int n_in,
                              void* d_out, int out_size, void* d_ws, size_t ws_size,
                              hipStream_t stream) {
    const float* coords = (const float*)d_in[0];
    const float* g0 = (const float*)d_in[1];
    const float* g1 = (const float*)d_in[2];
    const float* g2 = (const float*)d_in[3];
    const float* g3 = (const float*)d_in[4];
    const float* g4 = (const float*)d_in[5];
    const float* g5 = (const float*)d_in[6];
    const float* g6 = (const float*)d_in[7];
    const float* g7 = (const float*)d_in[8];
    const float* lpe = (const float*)d_in[9];
    const float* w0 = (const float*)d_in[10];
    const float* b0 = (const float*)d_in[11];
    const float* w1 = (const float*)d_in[12];
    const float* b1 = (const float*)d_in[13];
    const float* w2 = (const float*)d_in[14];
    const float* b2 = (const float*)d_in[15];
    f32x4* out = (f32x4*)d_out;

    int B = in_sizes[0] / 2;
    char* wsb = (char*)d_ws;

    if (ws_size >= WS_NEED && B == 1048576) {
        unsigned* part   = (unsigned*)(wsb + PART_OFF);
        unsigned* totals = (unsigned*)(wsb + TOT_OFF);
        float2*   scoord = (float2*)(wsb + SCOORD_OFF);
        unsigned* perm   = (unsigned*)(wsb + PERM_OFF);
        const float2* c2 = (const float2*)coords;

        hipMemsetAsync(totals, 0, NBUCKET * sizeof(unsigned), stream);
        prep_hist<<<4097, 256, 0, stream>>>(c2, part, totals, w0, b0, w1, b1, w2,
                                            (float*)d_ws);
        sort_offsets<<<NBUCKET, 256, 0, stream>>>(part, totals);
        sort_scatter<<<4096, 256, 0, stream>>>(c2, part, scoord, perm);

        colornet_sorted<<<4096, 256, 0, stream>>>(scoord, perm,
                                                  (const float2*)g0, (const float2*)g1,
                                                  (const float2*)g2, (const float2*)g3,
                                                  (const float2*)g4, (const float2*)g5,
                                                  (const float2*)g6, (const float2*)g7,
                                                  lpe, (const float*)d_ws, b2, out);
    } else {
        prep_kernel<<<1, 256, 0, stream>>>(w0, b0, w1, b1, w2, (float*)d_ws);
        colornet_fp32<<<B / 256, 256, 0, stream>>>(coords, g0, g1, g2, g3, g4, g5, g6, g7,
                                                   lpe, (const float*)d_ws, b2, out);
    }
}

// Round 10
// 122.049 us; speedup vs baseline: 1.7938x; 1.7938x over previous
//
#include <hip/hip_runtime.h>
#include <math.h>

typedef short bf16x8 __attribute__((ext_vector_type(8)));
typedef float f32x16 __attribute__((ext_vector_type(16)));
typedef float f32x4 __attribute__((ext_vector_type(4)));
typedef unsigned u32x4 __attribute__((ext_vector_type(4)));

#define NF 4
#define D0 8
#define LPE_OUT 24
#define NBUCKET 512                     // 32 v-rows x 16 u-cols
#define NROWS   512                     // hist/scatter chunks (2048 pts each)

// ---------------- ws byte layout ----------------
// [0,16896)  bf16 A-frags + C-layout biases (prep)
#define PART_OFF   17408ULL             // 512 x 512 u32 = 1 MB
#define TOT_OFF    1065984ULL           // totals[512]
#define LPE_OFF    1068544ULL           // 16641 cells x 48 B bf16
#define SCOORD_OFF 1867776ULL           // sorted float2, 8 MB
#define PERM_OFF   10256384ULL          // u32 perm, 4 MB
#define G6B_OFF    14450688ULL          // 1024^2 u32 (bf16x2), 4 MB
#define G7B_OFF    18644992ULL          // 2048^2 u32 (bf16x2), 16 MB
#define WS_NEED    35422208ULL

// ---------- bf16 helpers ----------
__device__ __forceinline__ unsigned f2bf(float x) {
    unsigned u = __float_as_uint(x);
    u = u + 0x7fffu + ((u >> 16) & 1u);
    return u >> 16;
}
__device__ __forceinline__ unsigned pkbf(float a, float b) {
    return f2bf(a) | (f2bf(b) << 16);
}
__device__ __forceinline__ float bflo(unsigned u) { return __uint_as_float(u << 16); }
__device__ __forceinline__ float bfhi(unsigned u) { return __uint_as_float(u & 0xffff0000u); }
__device__ __forceinline__ bf16x8 mkfrag(unsigned w0, unsigned w1, unsigned w2, unsigned w3) {
    u32x4 u = { w0, w1, w2, w3 };
    return __builtin_bit_cast(bf16x8, u);
}

// ---------- weight prep body (R3..R8-verified) ----------
__device__ void prep_body(const float* __restrict__ w0, const float* __restrict__ b0,
                          const float* __restrict__ w1, const float* __restrict__ b1,
                          const float* __restrict__ w2, float* __restrict__ ws, int t)
{
    unsigned short* a0 = (unsigned short*)ws;
    unsigned short* a1 = a0 + 2048;
    unsigned short* a2 = a1 + 4096;
    float* b0c = (float*)(a2 + 2048);
    float* b1c = b0c + 64;

    for (int e = t; e < 2048; e += 256) {
        int tile = e >> 9, lane = (e >> 3) & 63, j = e & 7;
        int m = tile >> 1, ks = tile & 1;
        int row = m * 32 + (lane & 31);
        int k = ks * 16 + (lane >> 5) * 8 + j;
        float v = (k < 26) ? w0[k * 64 + row] : 0.f;
        a0[e] = (unsigned short)f2bf(v);
    }
    for (int e = t; e < 4096; e += 256) {
        int tile = e >> 9, lane = (e >> 3) & 63, j = e & 7;
        int m = tile >> 2, ks = tile & 3;
        int row = m * 32 + (lane & 31);
        int k = ks * 16 + (lane >> 5) * 8 + j;
        a1[e] = (unsigned short)f2bf(w1[k * 64 + row]);
    }
    for (int e = t; e < 2048; e += 256) {
        int ks = e >> 9, lane = (e >> 3) & 63, j = e & 7;
        int row = lane & 31;
        int k = ks * 16 + (lane >> 5) * 8 + j;
        float v = (row < 4) ? w2[k * 4 + row] : 0.f;
        a2[e] = (unsigned short)f2bf(v);
    }
    if (t < 64) {
        int m = t >> 5, q5 = (t >> 4) & 1, r = t & 15;
        int row = (r & 3) + 8 * (r >> 2) + 4 * q5;
        b0c[(m * 2 + q5) * 16 + r] = b0[m * 32 + row];
        b1c[(m * 2 + q5) * 16 + r] = b1[m * 32 + row];
    }
}

__global__ void prep_kernel(const float* __restrict__ w0, const float* __restrict__ b0,
                            const float* __restrict__ w1, const float* __restrict__ b1,
                            const float* __restrict__ w2, float* __restrict__ ws)
{
    prep_body(w0, b0, w1, b1, w2, ws, threadIdx.x);
}

__device__ __forceinline__ int bucket_of(float cx, float cy) {
    float u = fminf(fmaxf(cx, 0.f), 1.f - 1e-6f);
    float v = fminf(fmaxf(cy, 0.f), 1.f - 1e-6f);
    return (int)(v * 32.f) * 16 + (int)(u * 16.f);
}

// ---------- fused pre-pass: g7/g6/LPE bf16 conversion + histogram + prep ----------
// blocks: [0,16384) g7 | [16384,20480) g6 | [20480,20676) LPE | [20676,21188) hist | 21188 prep
__global__ __launch_bounds__(256)
void fused_pre(const float2* __restrict__ g6, const float2* __restrict__ g7,
               const float4* __restrict__ lpe4, const float2* __restrict__ coords,
               unsigned* __restrict__ part, unsigned* __restrict__ totals,
               const float* __restrict__ w0, const float* __restrict__ b0,
               const float* __restrict__ w1, const float* __restrict__ b1,
               const float* __restrict__ w2, float* __restrict__ ws, char* __restrict__ wsb)
{
    int b = blockIdx.x, t = threadIdx.x;
    if (b < 16384) {
        int cell = b * 256 + t;
        float2 f = g7[cell];
        ((unsigned*)(wsb + G7B_OFF))[cell] = pkbf(f.x, f.y);
        return;
    }
    if (b < 20480) {
        int cell = (b - 16384) * 256 + t;
        float2 f = g6[cell];
        ((unsigned*)(wsb + G6B_OFF))[cell] = pkbf(f.x, f.y);
        return;
    }
    if (b < 20676) {
        int i = (b - 20480) * 256 + t;
        if (i < 49923) {
            float4 a = lpe4[i * 2], c = lpe4[i * 2 + 1];
            u32x4 o = { pkbf(a.x, a.y), pkbf(a.z, a.w), pkbf(c.x, c.y), pkbf(c.z, c.w) };
            ((u32x4*)(wsb + LPE_OFF))[i] = o;
        }
        return;
    }
    if (b < 21188) {
        int hb = b - 20676;
        __shared__ unsigned h[NBUCKET];
        h[t] = 0; h[t + 256] = 0;
        __syncthreads();
        for (int k = 0; k < 8; ++k) {
            float2 c = coords[hb * 2048 + k * 256 + t];
            atomicAdd(&h[bucket_of(c.x, c.y)], 1u);
        }
        __syncthreads();
        unsigned v0 = h[t], v1 = h[t + 256];
        part[hb * NBUCKET + t] = v0;
        part[hb * NBUCKET + 256 + t] = v1;
        if (v0) atomicAdd(&totals[t], v0);
        if (v1) atomicAdd(&totals[t + 256], v1);
        return;
    }
    prep_body(w0, b0, w1, b1, w2, ws, t);
}

// per-bucket offsets: prefix(totals) + column scan over 512 rows (2 rows/thread)
__global__ __launch_bounds__(256)
void sort_offsets(unsigned* __restrict__ part, const unsigned* __restrict__ totals)
{
    int bucket = blockIdx.x, t = threadIdx.x;
    __shared__ unsigned red[256];
    unsigned s0 = (t < bucket) ? totals[t] : 0u;
    if (t + 256 < bucket) s0 += totals[t + 256];
    red[t] = s0;
    __syncthreads();
    for (int off = 128; off > 0; off >>= 1) {
        if (t < off) red[t] += red[t + off];
        __syncthreads();
    }
    unsigned start = red[0];
    __syncthreads();

    unsigned l0 = part[(2 * t) * NBUCKET + bucket];
    unsigned l1 = part[(2 * t + 1) * NBUCKET + bucket];
    unsigned s = l0 + l1;
    __shared__ unsigned sc[256];
    sc[t] = s;
    __syncthreads();
    for (int off = 1; off < 256; off <<= 1) {
        unsigned v = (t >= off) ? sc[t - off] : 0u;
        __syncthreads();
        sc[t] += v;
        __syncthreads();
    }
    unsigned base = start + sc[t] - s;
    part[(2 * t) * NBUCKET + bucket] = base;
    part[(2 * t + 1) * NBUCKET + bucket] = base + l0;
}

__global__ __launch_bounds__(256)
void sort_scatter(const float2* __restrict__ coords, const unsigned* __restrict__ offs,
                  float2* __restrict__ scoord, unsigned* __restrict__ perm)
{
    __shared__ unsigned cnt[NBUCKET];
    __shared__ unsigned base[NBUCKET];
    int t = threadIdx.x, hb = blockIdx.x;
    cnt[t] = 0; cnt[t + 256] = 0;
    base[t] = offs[hb * NBUCKET + t];
    base[t + 256] = offs[hb * NBUCKET + 256 + t];
    __syncthreads();
    for (int k = 0; k < 8; ++k) {
        int i = hb * 2048 + k * 256 + t;
        float2 c = coords[i];
        int bb = bucket_of(c.x, c.y);
        unsigned r = atomicAdd(&cnt[bb], 1u);
        unsigned slot = base[bb] + r;
        scoord[slot] = c;
        perm[slot] = (unsigned)i;
    }
}

// ================= shared MLP pipeline (R4..R8-verified math) =================
__device__ __forceinline__ void mlp_pair(const unsigned (&B0)[2][2][4],
                                         const float* __restrict__ ws,
                                         const float* __restrict__ b2,
                                         int lane, int q5, f32x16 (&acc2)[2])
{
    const bf16x8* A0 = (const bf16x8*)ws;
    const bf16x8* A1 = (const bf16x8*)((const char*)ws + 4096);
    const bf16x8* A2 = (const bf16x8*)((const char*)ws + 12288);
    const float4* b0c = (const float4*)((const char*)ws + 16384);
    const float4* b1c = (const float4*)((const char*)ws + 16640);

    unsigned B1[4][2][4];
#pragma unroll
    for (int m = 0; m < 2; ++m) {
        f32x16 acc[2];
#pragma unroll
        for (int cc = 0; cc < 4; ++cc) {
            float4 bq = b0c[(m * 2 + q5) * 4 + cc];
#pragma unroll
            for (int n = 0; n < 2; ++n) {
                acc[n][4 * cc + 0] = bq.x;
                acc[n][4 * cc + 1] = bq.y;
                acc[n][4 * cc + 2] = bq.z;
                acc[n][4 * cc + 3] = bq.w;
            }
        }
#pragma unroll
        for (int ks = 0; ks < 2; ++ks) {
            bf16x8 af = A0[(m * 2 + ks) * 64 + lane];
#pragma unroll
            for (int n = 0; n < 2; ++n)
                acc[n] = __builtin_amdgcn_mfma_f32_32x32x16_bf16(
                    af, mkfrag(B0[ks][n][0], B0[ks][n][1], B0[ks][n][2], B0[ks][n][3]),
                    acc[n], 0, 0, 0);
        }
#pragma unroll
        for (int t = 0; t < 2; ++t) {
#pragma unroll
            for (int n = 0; n < 2; ++n)
#pragma unroll
                for (int c = 0; c < 2; ++c) {
                    int r0 = 2 * c + 8 * t;
                    int r1 = 2 * c + 8 * t + 4;
                    unsigned P0 = pkbf(fmaxf(acc[n][r0], 0.f), fmaxf(acc[n][r0 + 1], 0.f));
                    unsigned P1 = pkbf(fmaxf(acc[n][r1], 0.f), fmaxf(acc[n][r1 + 1], 0.f));
                    auto r = __builtin_amdgcn_permlane32_swap(P1, P0, false, false);
                    B1[2 * m + t][n][c] = r[1];
                    B1[2 * m + t][n][2 + c] = r[0];
                }
        }
    }

    unsigned B2[4][2][4];
#pragma unroll
    for (int m = 0; m < 2; ++m) {
        f32x16 acc[2];
#pragma unroll
        for (int cc = 0; cc < 4; ++cc) {
            float4 bq = b1c[(m * 2 + q5) * 4 + cc];
#pragma unroll
            for (int n = 0; n < 2; ++n) {
                acc[n][4 * cc + 0] = bq.x;
                acc[n][4 * cc + 1] = bq.y;
                acc[n][4 * cc + 2] = bq.z;
                acc[n][4 * cc + 3] = bq.w;
            }
        }
#pragma unroll
        for (int ks = 0; ks < 4; ++ks) {
            bf16x8 af = A1[(m * 4 + ks) * 64 + lane];
#pragma unroll
            for (int n = 0; n < 2; ++n)
                acc[n] = __builtin_amdgcn_mfma_f32_32x32x16_bf16(
                    af, mkfrag(B1[ks][n][0], B1[ks][n][1], B1[ks][n][2], B1[ks][n][3]),
                    acc[n], 0, 0, 0);
        }
#pragma unroll
        for (int t = 0; t < 2; ++t) {
#pragma unroll
            for (int n = 0; n < 2; ++n)
#pragma unroll
                for (int c = 0; c < 2; ++c) {
                    int r0 = 2 * c + 8 * t;
                    int r1 = 2 * c + 8 * t + 4;
                    unsigned P0 = pkbf(fmaxf(acc[n][r0], 0.f), fmaxf(acc[n][r0 + 1], 0.f));
                    unsigned P1 = pkbf(fmaxf(acc[n][r1], 0.f), fmaxf(acc[n][r1 + 1], 0.f));
                    auto r = __builtin_amdgcn_permlane32_swap(P1, P0, false, false);
                    B2[2 * m + t][n][c] = r[1];
                    B2[2 * m + t][n][2 + c] = r[0];
                }
        }
    }

#pragma unroll
    for (int n = 0; n < 2; ++n)
#pragma unroll
        for (int r = 0; r < 16; ++r) acc2[n][r] = (r < 4) ? b2[r] : 0.f;
#pragma unroll
    for (int ks = 0; ks < 4; ++ks) {
        bf16x8 af = A2[ks * 64 + lane];
#pragma unroll
        for (int n = 0; n < 2; ++n)
            acc2[n] = __builtin_amdgcn_mfma_f32_32x32x16_bf16(
                af, mkfrag(B2[ks][n][0], B2[ks][n][1], B2[ks][n][2], B2[ks][n][3]),
                acc2[n], 0, 0, 0);
    }
}

// ---------- main sorted kernel: bf16 g7/g6/LPE + fp32 low levels + hw trig ----------
__global__ __launch_bounds__(256, 4)
void colornet_sorted(const float2* __restrict__ pts,
                     const unsigned* __restrict__ perm,
                     const float2* __restrict__ g0, const float2* __restrict__ g1,
                     const float2* __restrict__ g2, const float2* __restrict__ g3,
                     const float2* __restrict__ g4, const float2* __restrict__ g5,
                     const float* __restrict__ ws,
                     const float* __restrict__ b2,
                     f32x4* __restrict__ out)
{
    const int lane = threadIdx.x & 63;
    const int wave = threadIdx.x >> 6;
    const int q5 = lane >> 5;
    int bid = blockIdx.x;
    int cpx = gridDim.x >> 3;
    bid = (bid & 7) * cpx + (bid >> 3);     // XCD-chunk swizzle (grid % 8 == 0)
    const int base_pt = bid * 256 + wave * 64;
    const char* wsb = (const char*)ws;

    float2 c = pts[base_pt + lane];
    float uA = fminf(fmaxf(c.x, 0.f), 1.f - 1e-6f);
    float vA = fminf(fmaxf(c.y, 0.f), 1.f - 1e-6f);

    float e0A = 0.f, e1A = 0.f;

    // ---- addresses (gx## avoids collision with kernel params b0/b1/b2) ----
#define ADDR(IDX, R) int gx##IDX; float lu##IDX, lv##IDX; \
    { float fu_ = uA * (float)((R) - 1), fv_ = vA * (float)((R) - 1); \
      int i0_ = (int)floorf(fu_), j0_ = (int)floorf(fv_); \
      i0_ = i0_ < 0 ? 0 : (i0_ > (R) - 2 ? (R) - 2 : i0_); \
      j0_ = j0_ < 0 ? 0 : (j0_ > (R) - 2 ? (R) - 2 : j0_); \
      lu##IDX = fu_ - (float)i0_; lv##IDX = fv_ - (float)j0_; \
      gx##IDX = i0_ + j0_ * (R); }
    ADDR(7, 2048) ADDR(6, 1024) ADDR(5, 512) ADDR(4, 256)
    ADDR(3, 128)  ADDR(2, 64)   ADDR(1, 32)  ADDR(0, 16)

    // ---- bf16 loads for g7/g6 (L2-critical) ----
    const unsigned* G7 = (const unsigned*)(wsb + G7B_OFF);
    const unsigned* G6 = (const unsigned*)(wsb + G6B_OFF);
    unsigned t7_0 = G7[gx7], t7_1 = G7[gx7 + 1], t7_2 = G7[gx7 + 2048], t7_3 = G7[gx7 + 2049];
    unsigned t6_0 = G6[gx6], t6_1 = G6[gx6 + 1], t6_2 = G6[gx6 + 1024], t6_3 = G6[gx6 + 1025];

    // ---- fp32 loads for g5..g0 (small, cache-trivial) ----
#define LOADF(IDX, R, G) \
    float2 f##IDX##_0 = (G)[gx##IDX],       f##IDX##_1 = (G)[gx##IDX + 1], \
           f##IDX##_2 = (G)[gx##IDX + (R)], f##IDX##_3 = (G)[gx##IDX + (R) + 1];
    LOADF(5, 512, g5) LOADF(4, 256, g4) LOADF(3, 128, g3)
    LOADF(2, 64,  g2) LOADF(1, 32,  g1) LOADF(0, 16,  g0)

    // ---- LPE bf16 (R5/R7-verified layout) ----
    float lu_pe, lv_pe;
    int lc;
    {
        float fu = uA * 128.f, fv = vA * 128.f;
        int i0 = (int)floorf(fu);
        int j0 = (int)floorf(fv);
        i0 = i0 < 0 ? 0 : (i0 > 127 ? 127 : i0);
        j0 = j0 < 0 ? 0 : (j0 > 127 ? 127 : j0);
        lu_pe = fu - (float)i0;
        lv_pe = fv - (float)j0;
        lc = (i0 + j0 * 129) * 3;
    }
    const u32x4* LP = (const u32x4*)(wsb + LPE_OFF);
    u32x4 L00a = LP[lc],       L00b = LP[lc + 1],   L00c = LP[lc + 2];
    u32x4 L10a = LP[lc + 3],   L10b = LP[lc + 4],   L10c = LP[lc + 5];
    u32x4 L01a = LP[lc + 387], L01b = LP[lc + 388], L01c = LP[lc + 389];
    u32x4 L11a = LP[lc + 390], L11b = LP[lc + 391], L11c = LP[lc + 392];

    // ---- hw trig in revolutions (R8-verified) ----
    float peA[16];
#pragma unroll
    for (int kf = 0; kf < NF; ++kf) {
        float au = lu_pe * (float)(1 << kf);
        float av = lv_pe * (float)(1 << kf);
        float fu_ = __builtin_amdgcn_fractf(au);
        float fv_ = __builtin_amdgcn_fractf(av);
        peA[kf]          = __builtin_amdgcn_cosf(fu_);
        peA[NF + kf]     = __builtin_amdgcn_sinf(fu_);
        peA[2 * NF + kf] = __builtin_amdgcn_cosf(fv_);
        peA[3 * NF + kf] = __builtin_amdgcn_sinf(fv_);
    }

    // ---- consume grids ----
#define WGT(IDX) float omu##IDX = 1.f - lu##IDX, omv##IDX = 1.f - lv##IDX; \
    float w00##IDX = omu##IDX * omv##IDX, w10##IDX = lu##IDX * omv##IDX, \
          w01##IDX = omu##IDX * lv##IDX,  w11##IDX = lu##IDX * lv##IDX;
    { WGT(7)
      e0A += bflo(t7_0) * w007 + bflo(t7_1) * w107 + bflo(t7_2) * w017 + bflo(t7_3) * w117;
      e1A += bfhi(t7_0) * w007 + bfhi(t7_1) * w107 + bfhi(t7_2) * w017 + bfhi(t7_3) * w117; }
    { WGT(6)
      e0A += bflo(t6_0) * w006 + bflo(t6_1) * w106 + bflo(t6_2) * w016 + bflo(t6_3) * w116;
      e1A += bfhi(t6_0) * w006 + bfhi(t6_1) * w106 + bfhi(t6_2) * w016 + bfhi(t6_3) * w116; }
#define SUMF(IDX) { WGT(IDX) \
      e0A += f##IDX##_0.x * w00##IDX + f##IDX##_1.x * w10##IDX + f##IDX##_2.x * w01##IDX + f##IDX##_3.x * w11##IDX; \
      e1A += f##IDX##_0.y * w00##IDX + f##IDX##_1.y * w10##IDX + f##IDX##_2.y * w01##IDX + f##IDX##_3.y * w11##IDX; }
    SUMF(5) SUMF(4) SUMF(3) SUMF(2) SUMF(1) SUMF(0)

    // ---- LPE consume (bf16, R5/R7-verified) ----
    float coeffA[LPE_OUT];
    {
        float omu = 1.f - lu_pe, omv = 1.f - lv_pe;
        float q00 = omu * omv, q10 = lu_pe * omv, q01 = omu * lv_pe, q11 = lu_pe * lv_pe;
#define LPW(W, A, B, C, Dd) \
        coeffA[2*(W)]   = bflo(A)*q00 + bflo(B)*q10 + bflo(C)*q01 + bflo(Dd)*q11; \
        coeffA[2*(W)+1] = bfhi(A)*q00 + bfhi(B)*q10 + bfhi(C)*q01 + bfhi(Dd)*q11;
        LPW(0,  L00a[0], L10a[0], L01a[0], L11a[0])
        LPW(1,  L00a[1], L10a[1], L01a[1], L11a[1])
        LPW(2,  L00a[2], L10a[2], L01a[2], L11a[2])
        LPW(3,  L00a[3], L10a[3], L01a[3], L11a[3])
        LPW(4,  L00b[0], L10b[0], L01b[0], L11b[0])
        LPW(5,  L00b[1], L10b[1], L01b[1], L11b[1])
        LPW(6,  L00b[2], L10b[2], L01b[2], L11b[2])
        LPW(7,  L00b[3], L10b[3], L01b[3], L11b[3])
        LPW(8,  L00c[0], L10c[0], L01c[0], L11c[0])
        LPW(9,  L00c[1], L10c[1], L01c[1], L11c[1])
        LPW(10, L00c[2], L10c[2], L01c[2], L11c[2])
        LPW(11, L00c[3], L10c[3], L01c[3], L11c[3])
#undef LPW
    }

    // ---- features -> bf16 pack ----
    unsigned fdA[16];
    {
        float feat[32];
        feat[0] = e0A; feat[1] = e1A;
#pragma unroll
        for (int q = 0; q < D0; ++q) feat[2 + q] = coeffA[q];
#pragma unroll
        for (int q = 0; q < 4 * NF; ++q) feat[2 + D0 + q] = coeffA[D0 + q] * peA[q];
#pragma unroll
        for (int q = 26; q < 32; ++q) feat[q] = 0.f;
#pragma unroll
        for (int i = 0; i < 16; ++i) fdA[i] = pkbf(feat[2 * i], feat[2 * i + 1]);
    }

    unsigned B0a[2][2][4];
#pragma unroll
    for (int ks = 0; ks < 2; ++ks)
#pragma unroll
        for (int j2 = 0; j2 < 4; ++j2) {
            unsigned a = fdA[8 * ks + j2];
            unsigned b = fdA[8 * ks + 4 + j2];
            auto r = __builtin_amdgcn_permlane32_swap(b, a, false, false);
            B0a[ks][1][j2] = r[0];
            B0a[ks][0][j2] = r[1];
        }

    f32x16 acc2[2];
    mlp_pair(B0a, ws, b2, lane, q5, acc2);

    if (lane < 32) {
#pragma unroll
        for (int n = 0; n < 2; ++n) {
            f32x4 o;
            o[0] = 1.f / (1.f + __expf(-acc2[n][0]));
            o[1] = 1.f / (1.f + __expf(-acc2[n][1]));
            o[2] = 1.f / (1.f + __expf(-acc2[n][2]));
            o[3] = 1.f / (1.f + __expf(-acc2[n][3]));
            int oi = (int)perm[base_pt + 32 * n + lane];
            __builtin_nontemporal_store(o, out + oi);
        }
    }
}

// ---------- fp32 unsorted fallback (R6..R8-verified) ----------
template<int R>
__device__ __forceinline__ void gather_level(const float* __restrict__ g,
                                             float u, float v,
                                             float& e0, float& e1) {
    const float scale = (float)(R - 1);
    float fu = u * scale, fv = v * scale;
    int i0 = (int)floorf(fu);
    int j0 = (int)floorf(fv);
    i0 = i0 < 0 ? 0 : (i0 > R - 2 ? R - 2 : i0);
    j0 = j0 < 0 ? 0 : (j0 > R - 2 ? R - 2 : j0);
    float lu = fu - (float)i0;
    float lv = fv - (float)j0;
    const float2* gg = (const float2*)g;
    int base = i0 + j0 * R;
    float2 f00 = gg[base];
    float2 f10 = gg[base + 1];
    float2 f01 = gg[base + R];
    float2 f11 = gg[base + R + 1];
    float omu = 1.f - lu, omv = 1.f - lv;
    float w00 = omu * omv, w10 = lu * omv, w01 = omu * lv, w11 = lu * lv;
    e0 += f00.x * w00 + f10.x * w10 + f01.x * w01 + f11.x * w11;
    e1 += f00.y * w00 + f10.y * w10 + f01.y * w01 + f11.y * w11;
}

__global__ __launch_bounds__(256, 4)
void colornet_fp32(const float* __restrict__ coords,
                   const float* __restrict__ g0, const float* __restrict__ g1,
                   const float* __restrict__ g2, const float* __restrict__ g3,
                   const float* __restrict__ g4, const float* __restrict__ g5,
                   const float* __restrict__ g6, const float* __restrict__ g7,
                   const float* __restrict__ lpe,
                   const float* __restrict__ ws,
                   const float* __restrict__ b2,
                   f32x4* __restrict__ out)
{
    const int lane = threadIdx.x & 63;
    const int wave = threadIdx.x >> 6;
    const int q5 = lane >> 5;
    const int base_pt = blockIdx.x * 256 + wave * 64;
    const int point = base_pt + lane;

    const float* cp = coords + 2 * point;
    float cx = __builtin_nontemporal_load(cp);
    float cy = __builtin_nontemporal_load(cp + 1);
    float uA = fminf(fmaxf(cx, 0.f), 1.f - 1e-6f);
    float vA = fminf(fmaxf(cy, 0.f), 1.f - 1e-6f);

    float e0 = 0.f, e1 = 0.f;
    gather_level<16>(g0, uA, vA, e0, e1);
    gather_level<32>(g1, uA, vA, e0, e1);
    gather_level<64>(g2, uA, vA, e0, e1);
    gather_level<128>(g3, uA, vA, e0, e1);
    gather_level<256>(g4, uA, vA, e0, e1);
    gather_level<512>(g5, uA, vA, e0, e1);
    gather_level<1024>(g6, uA, vA, e0, e1);
    gather_level<2048>(g7, uA, vA, e0, e1);

    float coeff[LPE_OUT];
    float lu_pe, lv_pe;
    {
        float fu = uA * 128.f, fv = vA * 128.f;
        int i0 = (int)floorf(fu);
        int j0 = (int)floorf(fv);
        i0 = i0 < 0 ? 0 : (i0 > 127 ? 127 : i0);
        j0 = j0 < 0 ? 0 : (j0 > 127 ? 127 : j0);
        lu_pe = fu - (float)i0;
        lv_pe = fv - (float)j0;
        int base = (i0 + j0 * 129) * LPE_OUT;
        const float4* p00 = (const float4*)(lpe + base);
        const float4* p10 = (const float4*)(lpe + base + LPE_OUT);
        const float4* p01 = (const float4*)(lpe + base + 129 * LPE_OUT);
        const float4* p11 = (const float4*)(lpe + base + 130 * LPE_OUT);
        float omu = 1.f - lu_pe, omv = 1.f - lv_pe;
        float w00 = omu * omv, w10 = lu_pe * omv, w01 = omu * lv_pe, w11 = lu_pe * lv_pe;
#pragma unroll
        for (int q = 0; q < 6; ++q) {
            float4 a = p00[q], bq = p10[q], cq = p01[q], dq = p11[q];
            coeff[4 * q + 0] = a.x * w00 + bq.x * w10 + cq.x * w01 + dq.x * w11;
            coeff[4 * q + 1] = a.y * w00 + bq.y * w10 + cq.y * w01 + dq.y * w11;
            coeff[4 * q + 2] = a.z * w00 + bq.z * w10 + cq.z * w01 + dq.z * w11;
            coeff[4 * q + 3] = a.w * w00 + bq.w * w10 + cq.w * w01 + dq.w * w11;
        }
    }

    float pe[16];
#pragma unroll
    for (int kf = 0; kf < NF; ++kf) {
        const float fr = 6.28318530717958647692f * (float)(1 << kf);
        float au = lu_pe * fr;
        float av = lv_pe * fr;
        pe[kf]          = __cosf(au);
        pe[NF + kf]     = __sinf(au);
        pe[2 * NF + kf] = __cosf(av);
        pe[3 * NF + kf] = __sinf(av);
    }

    float feat[32];
    feat[0] = e0; feat[1] = e1;
#pragma unroll
    for (int q = 0; q < D0; ++q) feat[2 + q] = coeff[q];
#pragma unroll
    for (int q = 0; q < 4 * NF; ++q) feat[2 + D0 + q] = coeff[D0 + q] * pe[q];
#pragma unroll
    for (int q = 26; q < 32; ++q) feat[q] = 0.f;

    unsigned fd[16];
#pragma unroll
    for (int i = 0; i < 16; ++i) fd[i] = pkbf(feat[2 * i], feat[2 * i + 1]);

    unsigned B0[2][2][4];
#pragma unroll
    for (int ks = 0; ks < 2; ++ks)
#pragma unroll
        for (int j2 = 0; j2 < 4; ++j2) {
            unsigned a = fd[8 * ks + j2];
            unsigned b = fd[8 * ks + 4 + j2];
            auto r = __builtin_amdgcn_permlane32_swap(b, a, false, false);
            B0[ks][1][j2] = r[0];
            B0[ks][0][j2] = r[1];
        }

    f32x16 acc2[2];
    mlp_pair(B0, ws, b2, lane, q5, acc2);
    if (lane < 32) {
#pragma unroll
        for (int n = 0; n < 2; ++n) {
            f32x4 o;
            o[0] = 1.f / (1.f + __expf(-acc2[n][0]));
            o[1] = 1.f / (1.f + __expf(-acc2[n][1]));
            o[2] = 1.f / (1.f + __expf(-acc2[n][2]));
            o[3] = 1.f / (1.f + __expf(-acc2[n][3]));
            __builtin_nontemporal_store(o, out + (base_pt + 32 * n + lane));
        }
    }
}

extern "C" void kernel_launch(void* const* d_in, const int* in_sizes, int n_in,
                              void* d_out, int out_size, void* d_ws, size_t ws_size,
                              hipStream_t stream) {
    const float* coords = (const float*)d_in[0];
    const float* g0 = (const float*)d_in[1];
    const float* g1 = (const float*)d_in[2];
    const float* g2 = (const float*)d_in[3];
    const float* g3 = (const float*)d_in[4];
    const float* g4 = (const float*)d_in[5];
    const float* g5 = (const float*)d_in[6];
    const float* g6 = (const float*)d_in[7];
    const float* g7 = (const float*)d_in[8];
    const float* lpe = (const float*)d_in[9];
    const float* w0 = (const float*)d_in[10];
    const float* b0 = (const float*)d_in[11];
    const float* w1 = (const float*)d_in[12];
    const float* b1 = (const float*)d_in[13];
    const float* w2 = (const float*)d_in[14];
    const float* b2 = (const float*)d_in[15];
    f32x4* out = (f32x4*)d_out;

    int B = in_sizes[0] / 2;
    char* wsb = (char*)d_ws;

    if (ws_size >= WS_NEED && B == 1048576) {
        unsigned* part   = (unsigned*)(wsb + PART_OFF);
        unsigned* totals = (unsigned*)(wsb + TOT_OFF);
        float2*   scoord = (float2*)(wsb + SCOORD_OFF);
        unsigned* perm   = (unsigned*)(wsb + PERM_OFF);
        const float2* c2 = (const float2*)coords;

        (void)hipMemsetAsync(totals, 0, NBUCKET * sizeof(unsigned), stream);
        fused_pre<<<21189, 256, 0, stream>>>((const float2*)g6, (const float2*)g7,
                                             (const float4*)lpe, c2, part, totals,
                                             w0, b0, w1, b1, w2, (float*)d_ws, wsb);
        sort_offsets<<<NBUCKET, 256, 0, stream>>>(part, totals);
        sort_scatter<<<NROWS, 256, 0, stream>>>(c2, part, scoord, perm);

        colornet_sorted<<<4096, 256, 0, stream>>>(scoord, perm,
                                                  (const float2*)g0, (const float2*)g1,
                                                  (const float2*)g2, (const float2*)g3,
                                                  (const float2*)g4, (const float2*)g5,
                                                  (const float*)d_ws, b2, out);
    } else {
        prep_kernel<<<1, 256, 0, stream>>>(w0, b0, w1, b1, w2, (float*)d_ws);
        colornet_fp32<<<B / 256, 256, 0, stream>>>(coords, g0, g1, g2, g3, g4, g5, g6, g7,
                                                   lpe, (const float*)d_ws, b2, out);
    }
}